// Round 1
// baseline (186.363 us; speedup 1.0000x reference)
//
#include <hip/hip_runtime.h>
#include <math.h>

#define D_MODEL 1024
#define D4 256            // D_MODEL/4
#define SEQ 2048
#define BATCH 32
#define NUM_PROTO 1024
#define TOPK 5
#define ALPHA 0.1f
#define EPS 1e-12f
#define CHUNKS 16         // l-chunks per batch for mean partials
#define CHUNK_ROWS (SEQ / CHUNKS)   // 128

// ---------------- block-wide sum reduce (256 threads, wave64) ----------------
__device__ __forceinline__ float block_reduce_sum_256(float v) {
    __shared__ float red[4];
    for (int o = 32; o; o >>= 1) v += __shfl_down(v, o, 64);
    const int wave = threadIdx.x >> 6;
    const int lane = threadIdx.x & 63;
    __syncthreads();                 // protect red[] from a previous call
    if (lane == 0) red[wave] = v;
    __syncthreads();
    return red[0] + red[1] + red[2] + red[3];
}

// ---------------- K1a: per-chunk partial sums over L ----------------
// grid = BATCH*CHUNKS blocks, 256 threads; thread t owns dims [4t,4t+4)
__global__ void mean_partial(const float* __restrict__ x, float* __restrict__ part) {
    const int blk = blockIdx.x;              // b*CHUNKS + c
    const int b = blk >> 4;
    const int c = blk & (CHUNKS - 1);
    const int t = threadIdx.x;
    const float4* xb = (const float4*)(x + (size_t)b * SEQ * D_MODEL
                                         + (size_t)c * CHUNK_ROWS * D_MODEL);
    float4 acc = {0.f, 0.f, 0.f, 0.f};
    for (int l = 0; l < CHUNK_ROWS; ++l) {
        float4 v = xb[(size_t)l * D4 + t];
        acc.x += v.x; acc.y += v.y; acc.z += v.z; acc.w += v.w;
    }
    ((float4*)part)[(size_t)blk * D4 + t] = acc;
}

// ---------------- K1b: reduce partials -> query (mean) ----------------
// grid = BATCH blocks, 256 threads
__global__ void mean_finish(const float* __restrict__ part, float* __restrict__ query) {
    const int b = blockIdx.x;
    const int t = threadIdx.x;
    float4 acc = {0.f, 0.f, 0.f, 0.f};
    for (int c = 0; c < CHUNKS; ++c) {
        float4 v = ((const float4*)part)[(size_t)(b * CHUNKS + c) * D4 + t];
        acc.x += v.x; acc.y += v.y; acc.z += v.z; acc.w += v.w;
    }
    const float s = 1.0f / (float)SEQ;
    acc.x *= s; acc.y *= s; acc.z *= s; acc.w *= s;
    ((float4*)query)[(size_t)b * D4 + t] = acc;
}

// ---------------- K2: scores[b][p] = dot(query[b],proto[p]) / max(||p||,eps) ----------------
// grid = NUM_PROTO blocks (one per prototype), 256 threads
__global__ void scores_kernel(const float* __restrict__ query,
                              const float* __restrict__ proto,
                              float* __restrict__ scores) {
    const int p = blockIdx.x;
    const int t = threadIdx.x;
    const float4 pv = ((const float4*)proto)[(size_t)p * D4 + t];
    const float pn2 = block_reduce_sum_256(pv.x * pv.x + pv.y * pv.y +
                                           pv.z * pv.z + pv.w * pv.w);
    const float inv_pn = 1.0f / fmaxf(sqrtf(pn2), EPS);
    for (int b = 0; b < BATCH; ++b) {
        const float4 q = ((const float4*)query)[(size_t)b * D4 + t];
        const float d = block_reduce_sum_256(q.x * pv.x + q.y * pv.y +
                                             q.z * pv.z + q.w * pv.w);
        if (t == 0) scores[(size_t)b * NUM_PROTO + p] = d * inv_pn;
    }
}

// ---------------- K3: per-batch top-5 + softmax + prototype aggregation ----------------
// grid = BATCH blocks, 256 threads
__global__ void topk_agg(const float* __restrict__ query,
                         const float* __restrict__ scores,
                         const float* __restrict__ proto,
                         float* __restrict__ agg) {
    const int b = blockIdx.x;
    const int t = threadIdx.x;

    // 1/max(||q||, eps)
    const float4 q = ((const float4*)query)[(size_t)b * D4 + t];
    const float qn2 = block_reduce_sum_256(q.x * q.x + q.y * q.y +
                                           q.z * q.z + q.w * q.w);
    const float inv_qn = 1.0f / fmaxf(sqrtf(qn2), EPS);

    __shared__ float sc[NUM_PROTO];
    for (int i = t; i < NUM_PROTO; i += 256)
        sc[i] = scores[(size_t)b * NUM_PROTO + i] * inv_qn;
    __syncthreads();

    __shared__ float topv[TOPK];
    __shared__ int   topi[TOPK];
    __shared__ float rv[4];
    __shared__ int   ri[4];

    for (int k = 0; k < TOPK; ++k) {
        // local best (ascending i + strict '>' keeps lowest index on ties)
        float bv = -INFINITY;
        int   bi = 0x7fffffff;
        for (int i = t; i < NUM_PROTO; i += 256) {
            const float v = sc[i];
            if (v > bv) { bv = v; bi = i; }
        }
        // wave reduce with lowest-index tie-break
        for (int o = 32; o; o >>= 1) {
            const float ov = __shfl_down(bv, o, 64);
            const int   oi = __shfl_down(bi, o, 64);
            if (ov > bv || (ov == bv && oi < bi)) { bv = ov; bi = oi; }
        }
        const int wave = t >> 6, lane = t & 63;
        __syncthreads();
        if (lane == 0) { rv[wave] = bv; ri[wave] = bi; }
        __syncthreads();
        if (t == 0) {
            float fv = rv[0]; int fi = ri[0];
            for (int w = 1; w < 4; ++w)
                if (rv[w] > fv || (rv[w] == fv && ri[w] < fi)) { fv = rv[w]; fi = ri[w]; }
            topv[k] = fv;
            topi[k] = fi;
            sc[fi] = -INFINITY;   // mask for next pass
        }
        __syncthreads();
    }

    // softmax over the 5 (topv[0] is the max — sorted descending)
    const float m = topv[0];
    float e[TOPK], s = 0.f;
    for (int k = 0; k < TOPK; ++k) { e[k] = expf(topv[k] - m); s += e[k]; }
    const float inv_s = 1.0f / s;

    // weighted sum of RAW prototypes
    float4 acc = {0.f, 0.f, 0.f, 0.f};
    for (int k = 0; k < TOPK; ++k) {
        const float a = e[k] * inv_s;
        const float4 pv = ((const float4*)proto)[(size_t)topi[k] * D4 + t];
        acc.x += a * pv.x; acc.y += a * pv.y; acc.z += a * pv.z; acc.w += a * pv.w;
    }
    ((float4*)agg)[(size_t)b * D4 + t] = acc;
}

// ---------------- K4: out = x + ALPHA * agg[b] (broadcast over L) ----------------
__global__ void residual_add(const float* __restrict__ x,
                             const float* __restrict__ agg,
                             float* __restrict__ out) {
    const size_t total4 = (size_t)BATCH * SEQ * D4;   // 16,777,216 float4
    const size_t stride = (size_t)gridDim.x * blockDim.x;
    for (size_t i = (size_t)blockIdx.x * blockDim.x + threadIdx.x;
         i < total4; i += stride) {
        const int d4 = (int)(i & (D4 - 1));
        const int b  = (int)(i >> 19);                // i / (SEQ*D4)
        const float4 xv = ((const float4*)x)[i];
        const float4 av = ((const float4*)agg)[(size_t)b * D4 + d4];
        float4 o;
        o.x = xv.x + ALPHA * av.x;
        o.y = xv.y + ALPHA * av.y;
        o.z = xv.z + ALPHA * av.z;
        o.w = xv.w + ALPHA * av.w;
        ((float4*)out)[i] = o;
    }
}

extern "C" void kernel_launch(void* const* d_in, const int* in_sizes, int n_in,
                              void* d_out, int out_size, void* d_ws, size_t ws_size,
                              hipStream_t stream) {
    const float* x     = (const float*)d_in[0];   // [32,2048,1024] fp32
    const float* proto = (const float*)d_in[1];   // [1024,1024] fp32
    float* out = (float*)d_out;

    // workspace layout (floats)
    float* ws      = (float*)d_ws;
    float* part    = ws;                                   // 512*1024 = 524288
    float* query   = part + (size_t)BATCH * CHUNKS * D_MODEL;  // 32768
    float* scores  = query + (size_t)BATCH * D_MODEL;          // 32768
    float* agg     = scores + (size_t)BATCH * NUM_PROTO;       // 32768

    mean_partial<<<BATCH * CHUNKS, 256, 0, stream>>>(x, part);
    mean_finish<<<BATCH, 256, 0, stream>>>(part, query);
    scores_kernel<<<NUM_PROTO, 256, 0, stream>>>(query, proto, scores);
    topk_agg<<<BATCH, 256, 0, stream>>>(query, scores, proto, agg);
    residual_add<<<4096, 256, 0, stream>>>(x, agg, out);
}

// Round 2
// 155.434 us; speedup vs baseline: 1.1990x; 1.1990x over previous
//
#include <hip/hip_runtime.h>
#include <math.h>

#define D_MODEL 1024
#define D4 256            // D_MODEL/4
#define SEQ 2048
#define BATCH 32
#define NUM_PROTO 1024
#define TOPK 5
#define ALPHA 0.1f
#define EPS 1e-12f
#define CHUNKS 64                    // l-chunks per batch for mean partials
#define CHUNK_ROWS (SEQ / CHUNKS)    // 32

typedef float f4v __attribute__((ext_vector_type(4)));

// ---------------- block-wide sum reduce (256 threads, wave64) ----------------
__device__ __forceinline__ float block_reduce_sum_256(float v) {
    __shared__ float red[4];
    for (int o = 32; o; o >>= 1) v += __shfl_down(v, o, 64);
    const int wave = threadIdx.x >> 6;
    const int lane = threadIdx.x & 63;
    __syncthreads();                 // protect red[] from a previous call
    if (lane == 0) red[wave] = v;
    __syncthreads();
    return (red[0] + red[1]) + (red[2] + red[3]);
}

// ---------------- K1a: per-chunk partial sums over L ----------------
// grid = BATCH*CHUNKS = 2048 blocks, 256 threads; thread t owns dims [4t,4t+4)
__global__ void mean_partial(const float* __restrict__ x, float* __restrict__ part) {
    const int blk = blockIdx.x;              // b*CHUNKS + c
    const int b = blk >> 6;
    const int c = blk & (CHUNKS - 1);
    const int t = threadIdx.x;
    const float4* xb = (const float4*)(x + (size_t)b * SEQ * D_MODEL
                                         + (size_t)c * CHUNK_ROWS * D_MODEL);
    float4 acc = {0.f, 0.f, 0.f, 0.f};
#pragma unroll 8
    for (int l = 0; l < CHUNK_ROWS; ++l) {
        float4 v = xb[(size_t)l * D4 + t];
        acc.x += v.x; acc.y += v.y; acc.z += v.z; acc.w += v.w;
    }
    ((float4*)part)[(size_t)blk * D4 + t] = acc;
}

// ---------------- K1b: reduce partials -> L2-NORMALIZED query ----------------
// grid = BATCH blocks, 256 threads
__global__ void mean_finish(const float* __restrict__ part, float* __restrict__ qn) {
    const int b = blockIdx.x;
    const int t = threadIdx.x;
    float4 acc = {0.f, 0.f, 0.f, 0.f};
    for (int c = 0; c < CHUNKS; ++c) {
        float4 v = ((const float4*)part)[(size_t)(b * CHUNKS + c) * D4 + t];
        acc.x += v.x; acc.y += v.y; acc.z += v.z; acc.w += v.w;
    }
    const float s = 1.0f / (float)SEQ;
    acc.x *= s; acc.y *= s; acc.z *= s; acc.w *= s;
    const float qn2 = block_reduce_sum_256(acc.x * acc.x + acc.y * acc.y +
                                           acc.z * acc.z + acc.w * acc.w);
    const float inv = 1.0f / fmaxf(sqrtf(qn2), EPS);
    float4 o = {acc.x * inv, acc.y * inv, acc.z * inv, acc.w * inv};
    ((float4*)qn)[(size_t)b * D4 + t] = o;
}

// ---------------- K2: scores[b][p] = dot(qn[b], proto[p]) / max(||p||,eps) ----
// grid = NUM_PROTO blocks (one per prototype), 256 threads; ONE barrier for the
// 32 batch dots (per-wave shfl reduce -> LDS [batch][wave]).
__global__ void scores_kernel(const float* __restrict__ qn,
                              const float* __restrict__ proto,
                              float* __restrict__ scores) {
    const int p = blockIdx.x;
    const int t = threadIdx.x;
    const int wave = t >> 6, lane = t & 63;
    const float4 pv = ((const float4*)proto)[(size_t)p * D4 + t];
    const float pn2 = block_reduce_sum_256(pv.x * pv.x + pv.y * pv.y +
                                           pv.z * pv.z + pv.w * pv.w);
    const float inv_pn = 1.0f / fmaxf(sqrtf(pn2), EPS);

    __shared__ float ps[BATCH][4];
    for (int b = 0; b < BATCH; ++b) {
        const float4 q = ((const float4*)qn)[(size_t)b * D4 + t];
        float d = q.x * pv.x + q.y * pv.y + q.z * pv.z + q.w * pv.w;
        for (int o = 32; o; o >>= 1) d += __shfl_down(d, o, 64);
        if (lane == 0) ps[b][wave] = d;
    }
    __syncthreads();
    if (t < BATCH) {
        const float s = (ps[t][0] + ps[t][1]) + (ps[t][2] + ps[t][3]);
        scores[(size_t)t * NUM_PROTO + p] = s * inv_pn;
    }
}

// ---------------- K3: per-batch top-5 + softmax + prototype aggregation ------
// grid = BATCH blocks, 256 threads
__global__ void topk_agg(const float* __restrict__ scores,
                         const float* __restrict__ proto,
                         float* __restrict__ agg) {
    const int b = blockIdx.x;
    const int t = threadIdx.x;

    __shared__ float sc[NUM_PROTO];
    for (int i = t; i < NUM_PROTO; i += 256)
        sc[i] = scores[(size_t)b * NUM_PROTO + i];
    __syncthreads();

    __shared__ float topv[TOPK];
    __shared__ int   topi[TOPK];
    __shared__ float rv[4];
    __shared__ int   ri[4];

    for (int k = 0; k < TOPK; ++k) {
        // local best (ascending i + strict '>' keeps lowest index on ties)
        float bv = -INFINITY;
        int   bi = 0x7fffffff;
        for (int i = t; i < NUM_PROTO; i += 256) {
            const float v = sc[i];
            if (v > bv) { bv = v; bi = i; }
        }
        // wave reduce with lowest-index tie-break
        for (int o = 32; o; o >>= 1) {
            const float ov = __shfl_down(bv, o, 64);
            const int   oi = __shfl_down(bi, o, 64);
            if (ov > bv || (ov == bv && oi < bi)) { bv = ov; bi = oi; }
        }
        const int wave = t >> 6, lane = t & 63;
        __syncthreads();
        if (lane == 0) { rv[wave] = bv; ri[wave] = bi; }
        __syncthreads();
        if (t == 0) {
            float fv = rv[0]; int fi = ri[0];
            for (int w = 1; w < 4; ++w)
                if (rv[w] > fv || (rv[w] == fv && ri[w] < fi)) { fv = rv[w]; fi = ri[w]; }
            topv[k] = fv;
            topi[k] = fi;
            sc[fi] = -INFINITY;   // mask for next pass
        }
        __syncthreads();
    }

    // softmax over the 5 (topv[0] is the max — sorted descending)
    const float m = topv[0];
    float e[TOPK], s = 0.f;
    for (int k = 0; k < TOPK; ++k) { e[k] = expf(topv[k] - m); s += e[k]; }
    const float inv_s = 1.0f / s;

    // weighted sum of RAW prototypes
    float4 acc = {0.f, 0.f, 0.f, 0.f};
    for (int k = 0; k < TOPK; ++k) {
        const float a = e[k] * inv_s;
        const float4 pv = ((const float4*)proto)[(size_t)topi[k] * D4 + t];
        acc.x += a * pv.x; acc.y += a * pv.y; acc.z += a * pv.z; acc.w += a * pv.w;
    }
    ((float4*)agg)[(size_t)b * D4 + t] = acc;
}

// ---------------- K4: out = x + ALPHA * agg[b] (broadcast over L) ------------
// grid = 8192 blocks; block = 8 consecutive rows of one batch; agg hoisted.
__global__ void residual_add(const float* __restrict__ x,
                             const float* __restrict__ agg,
                             float* __restrict__ out) {
    const int blk = blockIdx.x;
    const int b   = blk >> 8;                 // 256 blocks per batch
    const int seg = blk & 255;                // 8 rows each
    const int t = threadIdx.x;
    const size_t base = ((size_t)b * SEQ + (size_t)seg * 8) * D4 + t;

    const float4 av = ((const float4*)agg)[(size_t)b * D4 + t];
    const float ax = ALPHA * av.x, ay = ALPHA * av.y,
                az = ALPHA * av.z, aw = ALPHA * av.w;

    const f4v* x4 = (const f4v*)x;
    f4v* out4 = (f4v*)out;
#pragma unroll
    for (int r = 0; r < 8; ++r) {
        const size_t i = base + (size_t)r * D4;
        f4v xv = x4[i];
        f4v o;
        o.x = xv.x + ax; o.y = xv.y + ay; o.z = xv.z + az; o.w = xv.w + aw;
        __builtin_nontemporal_store(o, &out4[i]);
    }
}

extern "C" void kernel_launch(void* const* d_in, const int* in_sizes, int n_in,
                              void* d_out, int out_size, void* d_ws, size_t ws_size,
                              hipStream_t stream) {
    const float* x     = (const float*)d_in[0];   // [32,2048,1024] fp32
    const float* proto = (const float*)d_in[1];   // [1024,1024] fp32
    float* out = (float*)d_out;

    // workspace layout (floats)
    float* ws      = (float*)d_ws;
    float* part    = ws;                                        // 32*64*1024 = 2,097,152
    float* qn      = part + (size_t)BATCH * CHUNKS * D_MODEL;   // 32768
    float* scores  = qn + (size_t)BATCH * D_MODEL;              // 32768
    float* agg     = scores + (size_t)BATCH * NUM_PROTO;        // 32768

    mean_partial<<<BATCH * CHUNKS, 256, 0, stream>>>(x, part);
    mean_finish<<<BATCH, 256, 0, stream>>>(part, qn);
    scores_kernel<<<NUM_PROTO, 256, 0, stream>>>(qn, proto, scores);
    topk_agg<<<BATCH, 256, 0, stream>>>(scores, proto, agg);
    residual_add<<<8192, 256, 0, stream>>>(x, agg, out);
}